// Round 1
// baseline (409.560 us; speedup 1.0000x reference)
//
#include <hip/hip_runtime.h>

// Problem constants
#define BB      16384
#define IN_DIM  256
#define NE      32
#define H1D     64
#define H2D     256
#define H3D     128
#define NOUT    128

typedef __bf16 bf16_t;
typedef __bf16 bf16x4_t __attribute__((ext_vector_type(4)));
typedef __bf16 bf16x8  __attribute__((ext_vector_type(8)));
typedef float  f32x4   __attribute__((ext_vector_type(4)));

// ---- workspace layout (bytes): bf16 transposed weights ----
#define OFF_W1  ((size_t)0)                              // W1t: [E][64][256]
#define OFF_W2  (OFF_W1 + (size_t)NE*H1D*IN_DIM*2)       // W2t: [E][256][64]
#define OFF_W3  (OFF_W2 + (size_t)NE*H2D*H1D*2)          // W3t: [E][128][256]
#define OFF_W4  (OFF_W3 + (size_t)NE*H3D*H2D*2)          // W4t: [E][64][128]
#define OFF_W5  (OFF_W4 + (size_t)NE*H1D*H3D*2)          // W5t: [E][128][64]
#define OFF_WG  (OFF_W5 + (size_t)NE*NOUT*H1D*2)         // Wgt: [32][256]

// ---- prep: all weight transposes (incl. Wg) in ONE kernel (unchanged) ----
__global__ void cvt_w_all(const float* __restrict__ W1, const float* __restrict__ W2,
                          const float* __restrict__ W3, const float* __restrict__ W4,
                          const float* __restrict__ W5, const float* __restrict__ Wg,
                          bf16_t* __restrict__ W1t, bf16_t* __restrict__ W2t,
                          bf16_t* __restrict__ W3t, bf16_t* __restrict__ W4t,
                          bf16_t* __restrict__ W5t, bf16_t* __restrict__ Wgt)
{
    __shared__ float tile[64][65];
    const int j = blockIdx.x;
    const int e = j / 21;
    const int q = j % 21;
    const int tid = threadIdx.x;

    if (q == 20) {
        if (e >= 4) return;
        const int kt = e * 64;
        const int tx = tid & 31, ty = tid >> 5;
#pragma unroll
        for (int i = 0; i < 8; i++)
            tile[ty + i * 8][tx] = Wg[(size_t)(kt + ty + i * 8) * 32 + tx];
        __syncthreads();
        const int tx2 = tid & 63, ty2 = tid >> 6;
#pragma unroll
        for (int i = 0; i < 8; i++)
            Wgt[(size_t)(ty2 + i * 4) * 256 + kt + tx2] = (bf16_t)tile[tx2][ty2 + i * 4];
        return;
    }

    const float* src; bf16_t* dst; int K, N, kt, nt;
    if (q < 4)       { K = 256; N = 64;  kt = q * 64;            nt = 0;             src = W1; dst = W1t; }
    else if (q < 8)  { K = 64;  N = 256; kt = 0;                 nt = (q - 4) * 64;  src = W2; dst = W2t; }
    else if (q < 16) { K = 256; N = 128; int r = q - 8; kt = (r >> 1) * 64; nt = (r & 1) * 64; src = W3; dst = W3t; }
    else if (q < 18) { K = 128; N = 64;  kt = (q - 16) * 64;     nt = 0;             src = W4; dst = W4t; }
    else             { K = 64;  N = 128; kt = 0;                 nt = (q - 18) * 64; src = W5; dst = W5t; }
    src += (size_t)e * K * N;
    dst += (size_t)e * K * N;
    const int tx = tid & 63;
    const int ty = tid >> 6;
#pragma unroll
    for (int i = 0; i < 16; i++)
        tile[ty + i * 4][tx] = src[(size_t)(kt + ty + i * 4) * N + nt + tx];
    __syncthreads();
#pragma unroll
    for (int i = 0; i < 16; i++)
        dst[(size_t)(nt + ty + i * 4) * K + kt + tx] = (bf16_t)tile[tx][ty + i * 4];
}

// ---- swizzled LDS addressing ----
// Row-major [32 rows][1<<RS bytes]; 16B-granule XOR with (row&7):
// conflict-free for both the bf16x4 (8B) writes and bf16x8 (16B) reads.
template<int RS>
__device__ __forceinline__ void* swzp(char* base, int row, int byteoff) {
    const int g = byteoff >> 4;
    return (void*)(base + ((row << RS) | ((g ^ (row & 7)) << 4) | (byteoff & 15)));
}

// ---- generic swapped-operand layer ----
// D[f][b] = sum_k Wt[f][k] * H[b][k]; A = weight frag (global), B = act frag (LDS).
// Wave covers ALL 32 rows (m=0,1) and NT f-tiles starting at tile n0.
// Lane mapping: c = lane&15 (batch within 16-row group), q = lane>>4.
// D: f = tile*16 + 4q + r, b = m*16 + c  ->  bias+relu, pack bf16x4, 8B LDS write.
template<int K, int NT, int SRS, int DRS>
__device__ __forceinline__ void layerS(char* src, char* dst,
        const bf16_t* __restrict__ Wt, const float* __restrict__ bias,
        int n0, int q, int c)
{
    constexpr int KS = K / 32;
    f32x4 acc[NT][2];
#pragma unroll
    for (int nt = 0; nt < NT; nt++)
#pragma unroll
        for (int m = 0; m < 2; m++) acc[nt][m] = (f32x4){0.f, 0.f, 0.f, 0.f};
#pragma unroll
    for (int ks = 0; ks < KS; ks++) {
        bf16x8 bfr[2];
#pragma unroll
        for (int m = 0; m < 2; m++)
            bfr[m] = *(const bf16x8*)swzp<SRS>(src, m * 16 + c, ks * 64 + q * 16);
#pragma unroll
        for (int nt = 0; nt < NT; nt++) {
            bf16x8 afr = *(const bf16x8*)(Wt + (size_t)((n0 + nt) * 16 + c) * K + ks * 32 + q * 8);
#pragma unroll
            for (int m = 0; m < 2; m++)
                acc[nt][m] = __builtin_amdgcn_mfma_f32_16x16x32_bf16(afr, bfr[m], acc[nt][m], 0, 0, 0);
        }
    }
#pragma unroll
    for (int nt = 0; nt < NT; nt++) {
        const float4 bv = *(const float4*)(bias + (n0 + nt) * 16 + q * 4);
#pragma unroll
        for (int m = 0; m < 2; m++) {
            bf16x4_t hv = { (bf16_t)fmaxf(acc[nt][m][0] + bv.x, 0.f),
                            (bf16_t)fmaxf(acc[nt][m][1] + bv.y, 0.f),
                            (bf16_t)fmaxf(acc[nt][m][2] + bv.z, 0.f),
                            (bf16_t)fmaxf(acc[nt][m][3] + bv.w, 0.f) };
            *(bf16x4_t*)swzp<DRS>(dst, m * 16 + c, (n0 + nt) * 32 + q * 8) = hv;
        }
    }
}

// ---- L5 with gating accumulation into registers (2 f-tiles per wave) ----
__device__ __forceinline__ void l5_acc(char* bC2, const float* __restrict__ sGe,
    const bf16_t* __restrict__ W5e, const float* __restrict__ b5e,
    int wave, int q, int c, float oacc[2][2][4])
{
    f32x4 a2[2][2];
#pragma unroll
    for (int jj = 0; jj < 2; jj++)
#pragma unroll
        for (int m = 0; m < 2; m++) a2[jj][m] = (f32x4){0.f, 0.f, 0.f, 0.f};
#pragma unroll
    for (int ks = 0; ks < 2; ks++) {
        bf16x8 bfr[2];
#pragma unroll
        for (int m = 0; m < 2; m++)
            bfr[m] = *(const bf16x8*)swzp<7>(bC2, m * 16 + c, ks * 64 + q * 16);
#pragma unroll
        for (int jj = 0; jj < 2; jj++) {
            bf16x8 afr = *(const bf16x8*)(W5e + (size_t)((wave + 4 * jj) * 16 + c) * H1D + ks * 32 + q * 8);
#pragma unroll
            for (int m = 0; m < 2; m++)
                a2[jj][m] = __builtin_amdgcn_mfma_f32_16x16x32_bf16(afr, bfr[m], a2[jj][m], 0, 0, 0);
        }
    }
#pragma unroll
    for (int jj = 0; jj < 2; jj++) {
        const float4 bv = *(const float4*)(b5e + (wave + 4 * jj) * 16 + q * 4);
#pragma unroll
        for (int m = 0; m < 2; m++) {
            const float gv = sGe[m * 16 + c];
            oacc[jj][m][0] += gv * (a2[jj][m][0] + bv.x);
            oacc[jj][m][1] += gv * (a2[jj][m][1] + bv.y);
            oacc[jj][m][2] += gv * (a2[jj][m][2] + bv.z);
            oacc[jj][m][3] += gv * (a2[jj][m][3] + bv.w);
        }
    }
}

// ---- LDS carve (bytes), 32-row tiles, all XOR-swizzled, no padding ----
#define L_SX   0          // x   [32][256] bf16 = 16384  (RS=9)
#define L_BA   16384      // h2  [32][256] bf16 = 16384  (RS=9; aliases gating logits [32][36] f32)
#define L_BB   32768      // h3  [32][128] bf16 = 8192   (RS=8)
#define L_C1   40960      // h1  [32][64]  bf16 = 4096   (RS=7)
#define L_C2   45056      // h4  [32][64]  bf16 = 4096   (RS=7)
#define L_SG   49152      // g   [32e][32b] f32 = 4096
#define L_TOT  53248

// ---- main: 32-row tile, 4 waves, 512 blocks (2 independent blocks/CU) ----
__global__ __launch_bounds__(256, 2) void moe_main(
    const float* __restrict__ x,
    const bf16_t* __restrict__ W1t, const bf16_t* __restrict__ W2t,
    const bf16_t* __restrict__ W3t, const bf16_t* __restrict__ W4t,
    const bf16_t* __restrict__ W5t, const bf16_t* __restrict__ Wgt,
    const float* __restrict__ bg,
    const float* __restrict__ b1, const float* __restrict__ b2,
    const float* __restrict__ b3, const float* __restrict__ b4,
    const float* __restrict__ b5, float* __restrict__ out)
{
    __shared__ __align__(16) char lds[L_TOT];
    char* sX  = lds + L_SX;
    char* bA  = lds + L_BA;
    char* bB  = lds + L_BB;
    char* bC1 = lds + L_C1;
    char* bC2 = lds + L_C2;
    float* sG = (float*)(lds + L_SG);

    const int tid  = threadIdx.x;
    const int wave = tid >> 6;
    const int lane = tid & 63;
    const int c    = lane & 15;
    const int q    = lane >> 4;
    const int b0   = blockIdx.x * 32;

    // ---- stage x: 32x256 fp32 -> bf16, swizzled ----
    {
        const int r  = tid >> 3;
        const int c0 = (tid & 7) * 32;
        const float* sp = x + (size_t)(b0 + r) * IN_DIM + c0;
#pragma unroll
        for (int jj = 0; jj < 4; jj++) {
            const float4 v0 = *(const float4*)(sp + jj * 8);
            const float4 v1 = *(const float4*)(sp + jj * 8 + 4);
            bf16x8 o = { (bf16_t)v0.x, (bf16_t)v0.y, (bf16_t)v0.z, (bf16_t)v0.w,
                         (bf16_t)v1.x, (bf16_t)v1.y, (bf16_t)v1.z, (bf16_t)v1.w };
            *(bf16x8*)swzp<9>(sX, r, c0 * 2 + jj * 16) = o;
        }
    }
    __syncthreads();

    // ---- gating logits: D[e][b] -> sLgF [b][e] fp32 (pitch 36), aliases bA ----
    {
        const int t  = wave & 1;   // expert tile (0..1)
        const int mg = wave >> 1;  // row group (0..1)
        f32x4 acc = (f32x4){0.f, 0.f, 0.f, 0.f};
#pragma unroll
        for (int ks = 0; ks < 8; ks++) {
            bf16x8 bfr = *(const bf16x8*)swzp<9>(sX, mg * 16 + c, ks * 64 + q * 16);
            bf16x8 afr = *(const bf16x8*)(Wgt + (size_t)(t * 16 + c) * 256 + ks * 32 + q * 8);
            acc = __builtin_amdgcn_mfma_f32_16x16x32_bf16(afr, bfr, acc, 0, 0, 0);
        }
        const float4 bgv = *(const float4*)(bg + t * 16 + q * 4);
        float* sLgF = (float*)bA;
        *(float4*)(sLgF + (size_t)(mg * 16 + c) * 36 + t * 16 + q * 4) =
            (float4){acc[0] + bgv.x, acc[1] + bgv.y, acc[2] + bgv.z, acc[3] + bgv.w};
    }
    __syncthreads();
    // ---- softmax over experts -> sG [e][b] ----
    {
        const int r = tid >> 3;
        const int j = tid & 7;
        const float* sLgF = (const float*)bA;
        float4 l = *(const float4*)(sLgF + (size_t)r * 36 + j * 4);
        float mx = fmaxf(fmaxf(l.x, l.y), fmaxf(l.z, l.w));
#pragma unroll
        for (int off = 1; off < 8; off <<= 1) mx = fmaxf(mx, __shfl_xor(mx, off));
        float e0 = __expf(l.x - mx), e1 = __expf(l.y - mx),
              e2 = __expf(l.z - mx), e3 = __expf(l.w - mx);
        float sm = e0 + e1 + e2 + e3;
#pragma unroll
        for (int off = 1; off < 8; off <<= 1) sm += __shfl_xor(sm, off);
        const float rs = 1.f / sm;
        sG[(j * 4 + 0) * 32 + r] = e0 * rs;
        sG[(j * 4 + 1) * 32 + r] = e1 * rs;
        sG[(j * 4 + 2) * 32 + r] = e2 * rs;
        sG[(j * 4 + 3) * 32 + r] = e3 * rs;
    }
    __syncthreads();

    float oacc[2][2][4];
#pragma unroll
    for (int jj = 0; jj < 2; jj++)
#pragma unroll
        for (int m = 0; m < 2; m++)
#pragma unroll
            for (int r = 0; r < 4; r++) oacc[jj][m][r] = 0.f;

    for (int e = 0; e < NE; e++) {
        // Phase A: L1(e) -> bC1 ; merged L5(e-1): bC2 -> oacc (gated)
        layerS<256, 1, 9, 7>(sX, bC1, W1t + (size_t)e * H1D * IN_DIM, b1 + e * H1D, wave, q, c);
        if (e > 0)
            l5_acc(bC2, sG + (size_t)(e - 1) * 32, W5t + (size_t)(e - 1) * NOUT * H1D,
                   b5 + (size_t)(e - 1) * NOUT, wave, q, c, oacc);
        __syncthreads();
        // Phase B: L2: bC1 [32x64] -> bA [32x256]
        layerS<64, 4, 7, 9>(bC1, bA, W2t + (size_t)e * H2D * H1D, b2 + e * H2D, wave * 4, q, c);
        __syncthreads();
        // Phase C: L3: bA [32x256] -> bB [32x128]
        layerS<256, 2, 9, 8>(bA, bB, W3t + (size_t)e * H3D * H2D, b3 + e * H3D, wave * 2, q, c);
        __syncthreads();
        // Phase D: L4: bB [32x128] -> bC2 [32x64]
        layerS<128, 1, 8, 7>(bB, bC2, W4t + (size_t)e * H1D * H3D, b4 + e * H1D, wave, q, c);
        __syncthreads();
    }
    // Final L5 for e=31
    l5_acc(bC2, sG + (size_t)(NE - 1) * 32, W5t + (size_t)(NE - 1) * NOUT * H1D,
           b5 + (size_t)(NE - 1) * NOUT, wave, q, c, oacc);

    // ---- store: coalesced float4; lane owns rows {c, 16+c}, cols (wave+4j)*16+4q..+3 ----
#pragma unroll
    for (int jj = 0; jj < 2; jj++)
#pragma unroll
        for (int m = 0; m < 2; m++)
            *(float4*)(out + (size_t)(b0 + m * 16 + c) * NOUT + (wave + 4 * jj) * 16 + q * 4) =
                (float4){oacc[jj][m][0], oacc[jj][m][1], oacc[jj][m][2], oacc[jj][m][3]};
}

extern "C" void kernel_launch(void* const* d_in, const int* in_sizes, int n_in,
                              void* d_out, int out_size, void* d_ws, size_t ws_size,
                              hipStream_t stream)
{
    (void)in_sizes; (void)n_in; (void)out_size; (void)ws_size;
    const float* x  = (const float*)d_in[0];
    const float* Wg = (const float*)d_in[1];
    const float* bg = (const float*)d_in[2];
    const float* W1 = (const float*)d_in[3];
    const float* b1 = (const float*)d_in[4];
    const float* W2 = (const float*)d_in[5];
    const float* b2 = (const float*)d_in[6];
    const float* W3 = (const float*)d_in[7];
    const float* b3 = (const float*)d_in[8];
    const float* W4 = (const float*)d_in[9];
    const float* b4 = (const float*)d_in[10];
    const float* W5 = (const float*)d_in[11];
    const float* b5 = (const float*)d_in[12];

    char* ws = (char*)d_ws;
    bf16_t* W1t = (bf16_t*)(ws + OFF_W1);
    bf16_t* W2t = (bf16_t*)(ws + OFF_W2);
    bf16_t* W3t = (bf16_t*)(ws + OFF_W3);
    bf16_t* W4t = (bf16_t*)(ws + OFF_W4);
    bf16_t* W5t = (bf16_t*)(ws + OFF_W5);
    bf16_t* Wgt = (bf16_t*)(ws + OFF_WG);
    float*  outp = (float*)d_out;

    cvt_w_all<<<dim3(NE * 21), dim3(256), 0, stream>>>(W1, W2, W3, W4, W5, Wg,
                                                       W1t, W2t, W3t, W4t, W5t, Wgt);
    moe_main<<<dim3(BB / 32), dim3(256), 0, stream>>>(x, W1t, W2t, W3t, W4t, W5t, Wgt, bg,
                                                      b1, b2, b3, b4, b5, outp);
}

// Round 2
// 244.083 us; speedup vs baseline: 1.6780x; 1.6780x over previous
//
#include <hip/hip_runtime.h>

// Problem constants
#define BB      16384
#define IN_DIM  256
#define NE      32
#define H1D     64
#define H2D     256
#define H3D     128
#define NOUT    128

typedef __bf16 bf16_t;
typedef __bf16 bf16x4_t __attribute__((ext_vector_type(4)));
typedef __bf16 bf16x8  __attribute__((ext_vector_type(8)));
typedef float  f32x4   __attribute__((ext_vector_type(4)));

// ---- workspace layout ----
// Wf: fragment-ordered weights, [E][81920 elems] bf16, per-expert layout:
//   L1 off 0     : 4 tiles x 8 ks   (W1: K=256 -> 64 f)
//   L2 off 16384 : 16 tiles x 2 ks  (W2: K=64  -> 256 f)
//   L3 off 32768 : 8 tiles x 8 ks   (W3: K=256 -> 128 f)
//   L4 off 65536 : 4 tiles x 4 ks   (W4: K=128 -> 64 f)
//   L5 off 73728 : 8 tiles x 2 ks   (W5: K=64  -> 128 f)
// frag element: Wf[((tile*KS + ks)*64 + lane)*8 + j] = W[k0+j][tile*16 + (lane&15)],
//   k0 = ks*32 + (lane>>4)*8.  A wave-load of one fragment = contiguous 1024 B.
#define OFF_WF   ((size_t)0)
#define OFF_WGF  ((size_t)NE * 81920 * 2)     // Wg frags: 2 tiles x 8 ks = 16 KB

// ---- prep: build fragment-ordered bf16 weights ----
__global__ void build_frags(const float* __restrict__ W1, const float* __restrict__ W2,
                            const float* __restrict__ W3, const float* __restrict__ W4,
                            const float* __restrict__ W5, const float* __restrict__ Wg,
                            bf16_t* __restrict__ Wf, bf16_t* __restrict__ Wgf)
{
    const int b = blockIdx.x;
    const int tid = threadIdx.x;
    const float* src = Wg; bf16_t* dst = Wgf; int K = 256, N = 32;
    if (b < 160) {
        const int e = b / 5, l = b % 5;
        switch (l) {
        case 0: src = W1 + (size_t)e*256*64;  dst = Wf + (size_t)e*81920 + 0;     K = 256; N = 64;  break;
        case 1: src = W2 + (size_t)e*64*256;  dst = Wf + (size_t)e*81920 + 16384; K = 64;  N = 256; break;
        case 2: src = W3 + (size_t)e*256*128; dst = Wf + (size_t)e*81920 + 32768; K = 256; N = 128; break;
        case 3: src = W4 + (size_t)e*128*64;  dst = Wf + (size_t)e*81920 + 65536; K = 128; N = 64;  break;
        case 4: src = W5 + (size_t)e*64*128;  dst = Wf + (size_t)e*81920 + 73728; K = 64;  N = 128; break;
        }
    }
    const int KS = K / 32;
    const int total = (N / 16) * KS * 64;
    for (int t = tid; t < total; t += 256) {
        const int lane = t & 63;
        const int rem  = t >> 6;
        const int ks   = rem % KS;
        const int tile = rem / KS;
        const int f  = tile * 16 + (lane & 15);
        const int k0 = ks * 32 + (lane >> 4) * 8;
        bf16x8 o;
#pragma unroll
        for (int j = 0; j < 8; j++) o[j] = (bf16_t)src[(size_t)(k0 + j) * N + f];
        *(bf16x8*)(dst + (size_t)t * 8) = o;
    }
}

// ---- swizzled LDS addressing (verified round 1): 16B-granule XOR with row&7 ----
template<int RS>
__device__ __forceinline__ void* swzp(char* base, int row, int byteoff) {
    const int g = byteoff >> 4;
    return (void*)(base + ((row << RS) | ((g ^ (row & 7)) << 4) | (byteoff & 15)));
}

// ---- LDS carve: 64-row tile ----
#define L_SX   0          // x  [64][512B]  RS=9  32 KB
#define L_H1   32768      // h1 [64][128B]  RS=7   8 KB
#define L_H2   40960      // h2 [64][512B]  RS=9  32 KB (alias gating logits [64][36] f32)
#define L_H3   73728      // h3 [64][256B]  RS=8  16 KB
#define L_H4   90112      // h4 [64][128B]  RS=7   8 KB
#define L_SG   98304      // g  [32e][64b] f32     8 KB
#define L_TOT  106496

// ---- main: 64-row tile, 8 waves, 256 blocks, frag weights + reg prefetch ----
__global__ __launch_bounds__(512, 2) void moe_main(
    const float* __restrict__ x, const bf16_t* __restrict__ Wf,
    const bf16_t* __restrict__ Wgf, const float* __restrict__ bg,
    const float* __restrict__ b1, const float* __restrict__ b2,
    const float* __restrict__ b3, const float* __restrict__ b4,
    const float* __restrict__ b5, float* __restrict__ out)
{
    __shared__ __align__(16) char lds[L_TOT];
    char* sX = lds + L_SX;
    char* h1 = lds + L_H1;
    char* h2 = lds + L_H2;
    char* h3 = lds + L_H3;
    char* h4 = lds + L_H4;
    float* sG = (float*)(lds + L_SG);

    const int tid  = threadIdx.x;
    const int w    = tid >> 6;          // wave 0..7
    const int lane = tid & 63;
    const int c    = lane & 15;
    const int q    = lane >> 4;
    const int tq   = w & 3;             // tile for L1/L4
    const int mh   = (w >> 2) * 2;      // m-half base for L1/L4
    const int b0   = blockIdx.x * 64;

    // ---- stage x: 64x256 fp32 -> bf16, swizzled ----
    {
        const int r  = tid >> 3;
        const int c0 = (tid & 7) * 32;
        const float* sp = x + (size_t)(b0 + r) * IN_DIM + c0;
#pragma unroll
        for (int jj = 0; jj < 4; jj++) {
            const float4 v0 = *(const float4*)(sp + jj * 8);
            const float4 v1 = *(const float4*)(sp + jj * 8 + 4);
            bf16x8 o = { (bf16_t)v0.x, (bf16_t)v0.y, (bf16_t)v0.z, (bf16_t)v0.w,
                         (bf16_t)v1.x, (bf16_t)v1.y, (bf16_t)v1.z, (bf16_t)v1.w };
            *(bf16x8*)swzp<9>(sX, r, c0 * 2 + jj * 16) = o;
        }
    }

    // ---- weight fragment registers (single-buffered; liveness is disjoint) ----
    bf16x8 wA[8];      // L1, tile tq
    bf16x8 wB[2][2];   // L2, tiles w*2 .. w*2+1
    bf16x8 wC[8];      // L3, tile w
    bf16x8 wD[4];      // L4, tile tq
    bf16x8 wE[2];      // L5, tile w

    // pre-issue wA(0), wB(0) — pure global loads, overlap with staging/gating
    {
        const bf16_t* We = Wf;   // e = 0
#pragma unroll
        for (int ks = 0; ks < 8; ks++)
            wA[ks] = *(const bf16x8*)(We + ((size_t)(tq * 8 + ks) * 64 + lane) * 8);
#pragma unroll
        for (int nt = 0; nt < 2; nt++)
#pragma unroll
            for (int ks = 0; ks < 2; ks++)
                wB[nt][ks] = *(const bf16x8*)(We + 16384 + ((size_t)((w * 2 + nt) * 2 + ks) * 64 + lane) * 8);
    }
    __syncthreads();

    // ---- gating logits: wave (t = w&1 expert-tile, m = w>>1 row-tile) ----
    {
        const int t = w & 1, m = w >> 1;
        f32x4 acc = (f32x4){0.f, 0.f, 0.f, 0.f};
#pragma unroll
        for (int ks = 0; ks < 8; ks++) {
            bf16x8 xa = *(const bf16x8*)swzp<9>(sX, m * 16 + c, ks * 64 + q * 16);
            bf16x8 wg = *(const bf16x8*)(Wgf + ((size_t)(t * 8 + ks) * 64 + lane) * 8);
            acc = __builtin_amdgcn_mfma_f32_16x16x32_bf16(wg, xa, acc, 0, 0, 0);
        }
        const float4 bgv = *(const float4*)(bg + t * 16 + q * 4);
        float* sLgF = (float*)h2;    // [64][36] f32
        *(float4*)(sLgF + (size_t)(m * 16 + c) * 36 + t * 16 + q * 4) =
            (float4){acc[0] + bgv.x, acc[1] + bgv.y, acc[2] + bgv.z, acc[3] + bgv.w};
    }
    __syncthreads();
    // ---- softmax over experts -> sG [e][b] ----
    {
        const int r = tid >> 3;
        const int j = tid & 7;
        const float* sLgF = (const float*)h2;
        float4 l = *(const float4*)(sLgF + (size_t)r * 36 + j * 4);
        float mx = fmaxf(fmaxf(l.x, l.y), fmaxf(l.z, l.w));
#pragma unroll
        for (int off = 1; off < 8; off <<= 1) mx = fmaxf(mx, __shfl_xor(mx, off));
        float e0 = __expf(l.x - mx), e1 = __expf(l.y - mx),
              e2 = __expf(l.z - mx), e3 = __expf(l.w - mx);
        float sm = e0 + e1 + e2 + e3;
#pragma unroll
        for (int off = 1; off < 8; off <<= 1) sm += __shfl_xor(sm, off);
        const float rs = 1.f / sm;
        sG[(j * 4 + 0) * 64 + r] = e0 * rs;
        sG[(j * 4 + 1) * 64 + r] = e1 * rs;
        sG[(j * 4 + 2) * 64 + r] = e2 * rs;
        sG[(j * 4 + 3) * 64 + r] = e3 * rs;
    }
    __syncthreads();

    float oacc[4][4];
#pragma unroll
    for (int m = 0; m < 4; m++)
#pragma unroll
        for (int r = 0; r < 4; r++) oacc[m][r] = 0.f;

    auto do_l5 = [&](int ep) {
        const float4 bv = *(const float4*)(b5 + (size_t)ep * NOUT + w * 16 + q * 4);
#pragma unroll
        for (int m = 0; m < 4; m++) {
            f32x4 acc = (f32x4){0.f, 0.f, 0.f, 0.f};
#pragma unroll
            for (int ks = 0; ks < 2; ks++) {
                bf16x8 ha = *(const bf16x8*)swzp<7>(h4, m * 16 + c, ks * 64 + q * 16);
                acc = __builtin_amdgcn_mfma_f32_16x16x32_bf16(wE[ks], ha, acc, 0, 0, 0);
            }
            const float gv = sG[ep * 64 + m * 16 + c];
            oacc[m][0] += gv * (acc[0] + bv.x);
            oacc[m][1] += gv * (acc[1] + bv.y);
            oacc[m][2] += gv * (acc[2] + bv.z);
            oacc[m][3] += gv * (acc[3] + bv.w);
        }
    };

    for (int e = 0; e < NE; e++) {
        const bf16_t* We  = Wf + (size_t)e * 81920;
        const bf16_t* Wen = Wf + (size_t)((e + 1) & 31) * 81920;

        // ---- Phase A: L1(e) -> h1 (tile tq, rows mh..mh+1); L5(e-1) -> oacc ----
        {
            const float4 bv = *(const float4*)(b1 + (size_t)e * H1D + tq * 16 + q * 4);
#pragma unroll
            for (int mm = 0; mm < 2; mm++) {
                const int m = mh + mm;
                f32x4 acc = (f32x4){0.f, 0.f, 0.f, 0.f};
#pragma unroll
                for (int ks = 0; ks < 8; ks++) {
                    bf16x8 xa = *(const bf16x8*)swzp<9>(sX, m * 16 + c, ks * 64 + q * 16);
                    acc = __builtin_amdgcn_mfma_f32_16x16x32_bf16(wA[ks], xa, acc, 0, 0, 0);
                }
                bf16x4_t hv = { (bf16_t)fmaxf(acc[0] + bv.x, 0.f),
                                (bf16_t)fmaxf(acc[1] + bv.y, 0.f),
                                (bf16_t)fmaxf(acc[2] + bv.z, 0.f),
                                (bf16_t)fmaxf(acc[3] + bv.w, 0.f) };
                *(bf16x4_t*)swzp<7>(h1, m * 16 + c, tq * 32 + q * 8) = hv;
            }
        }
        if (e > 0) do_l5(e - 1);
        __syncthreads();

        // ---- Phase B: issue wC(e), wD(e); L2: h1 -> h2 (tiles w*2..+1, all m) ----
#pragma unroll
        for (int ks = 0; ks < 8; ks++)
            wC[ks] = *(const bf16x8*)(We + 32768 + ((size_t)(w * 8 + ks) * 64 + lane) * 8);
#pragma unroll
        for (int ks = 0; ks < 4; ks++)
            wD[ks] = *(const bf16x8*)(We + 65536 + ((size_t)(tq * 4 + ks) * 64 + lane) * 8);
        {
            float4 bv[2];
#pragma unroll
            for (int nt = 0; nt < 2; nt++)
                bv[nt] = *(const float4*)(b2 + (size_t)e * H2D + (w * 2 + nt) * 16 + q * 4);
#pragma unroll
            for (int m = 0; m < 4; m++) {
                bf16x8 ha[2];
#pragma unroll
                for (int ks = 0; ks < 2; ks++)
                    ha[ks] = *(const bf16x8*)swzp<7>(h1, m * 16 + c, ks * 64 + q * 16);
                f32x4 acc[2];
#pragma unroll
                for (int nt = 0; nt < 2; nt++) acc[nt] = (f32x4){0.f, 0.f, 0.f, 0.f};
#pragma unroll
                for (int nt = 0; nt < 2; nt++)
#pragma unroll
                    for (int ks = 0; ks < 2; ks++)
                        acc[nt] = __builtin_amdgcn_mfma_f32_16x16x32_bf16(wB[nt][ks], ha[ks], acc[nt], 0, 0, 0);
#pragma unroll
                for (int nt = 0; nt < 2; nt++) {
                    bf16x4_t hv = { (bf16_t)fmaxf(acc[nt][0] + bv[nt].x, 0.f),
                                    (bf16_t)fmaxf(acc[nt][1] + bv[nt].y, 0.f),
                                    (bf16_t)fmaxf(acc[nt][2] + bv[nt].z, 0.f),
                                    (bf16_t)fmaxf(acc[nt][3] + bv[nt].w, 0.f) };
                    *(bf16x4_t*)swzp<9>(h2, m * 16 + c, (w * 2 + nt) * 32 + q * 8) = hv;
                }
            }
        }
        __syncthreads();

        // ---- Phase C: issue wA(e+1), wE(e); L3: h2 -> h3 (tile w, all m) ----
#pragma unroll
        for (int ks = 0; ks < 8; ks++)
            wA[ks] = *(const bf16x8*)(Wen + ((size_t)(tq * 8 + ks) * 64 + lane) * 8);
#pragma unroll
        for (int ks = 0; ks < 2; ks++)
            wE[ks] = *(const bf16x8*)(We + 73728 + ((size_t)(w * 2 + ks) * 64 + lane) * 8);
        {
            const float4 bv = *(const float4*)(b3 + (size_t)e * H3D + w * 16 + q * 4);
#pragma unroll
            for (int m = 0; m < 4; m++) {
                f32x4 acc = (f32x4){0.f, 0.f, 0.f, 0.f};
#pragma unroll
                for (int ks = 0; ks < 8; ks++) {
                    bf16x8 ha = *(const bf16x8*)swzp<9>(h2, m * 16 + c, ks * 64 + q * 16);
                    acc = __builtin_amdgcn_mfma_f32_16x16x32_bf16(wC[ks], ha, acc, 0, 0, 0);
                }
                bf16x4_t hv = { (bf16_t)fmaxf(acc[0] + bv.x, 0.f),
                                (bf16_t)fmaxf(acc[1] + bv.y, 0.f),
                                (bf16_t)fmaxf(acc[2] + bv.z, 0.f),
                                (bf16_t)fmaxf(acc[3] + bv.w, 0.f) };
                *(bf16x4_t*)swzp<8>(h3, m * 16 + c, w * 32 + q * 8) = hv;
            }
        }
        __syncthreads();

        // ---- Phase D: issue wB(e+1); L4: h3 -> h4 (tile tq, rows mh..mh+1) ----
#pragma unroll
        for (int nt = 0; nt < 2; nt++)
#pragma unroll
            for (int ks = 0; ks < 2; ks++)
                wB[nt][ks] = *(const bf16x8*)(Wen + 16384 + ((size_t)((w * 2 + nt) * 2 + ks) * 64 + lane) * 8);
        {
            const float4 bv = *(const float4*)(b4 + (size_t)e * H1D + tq * 16 + q * 4);
#pragma unroll
            for (int mm = 0; mm < 2; mm++) {
                const int m = mh + mm;
                f32x4 acc = (f32x4){0.f, 0.f, 0.f, 0.f};
#pragma unroll
                for (int ks = 0; ks < 4; ks++) {
                    bf16x8 ha = *(const bf16x8*)swzp<8>(h3, m * 16 + c, ks * 64 + q * 16);
                    acc = __builtin_amdgcn_mfma_f32_16x16x32_bf16(wD[ks], ha, acc, 0, 0, 0);
                }
                bf16x4_t hv = { (bf16_t)fmaxf(acc[0] + bv.x, 0.f),
                                (bf16_t)fmaxf(acc[1] + bv.y, 0.f),
                                (bf16_t)fmaxf(acc[2] + bv.z, 0.f),
                                (bf16_t)fmaxf(acc[3] + bv.w, 0.f) };
                *(bf16x4_t*)swzp<7>(h4, m * 16 + c, tq * 32 + q * 8) = hv;
            }
        }
        __syncthreads();
    }

    // ---- final L5 for e = 31 ----
    do_l5(NE - 1);

    // ---- store: lane owns rows m*16+c, cols w*16 + q*4 .. +3 ----
#pragma unroll
    for (int m = 0; m < 4; m++)
        *(float4*)(out + (size_t)(b0 + m * 16 + c) * NOUT + w * 16 + q * 4) =
            (float4){oacc[m][0], oacc[m][1], oacc[m][2], oacc[m][3]};
}

extern "C" void kernel_launch(void* const* d_in, const int* in_sizes, int n_in,
                              void* d_out, int out_size, void* d_ws, size_t ws_size,
                              hipStream_t stream)
{
    (void)in_sizes; (void)n_in; (void)out_size; (void)ws_size;
    const float* x  = (const float*)d_in[0];
    const float* Wg = (const float*)d_in[1];
    const float* bg = (const float*)d_in[2];
    const float* W1 = (const float*)d_in[3];
    const float* b1 = (const float*)d_in[4];
    const float* W2 = (const float*)d_in[5];
    const float* b2 = (const float*)d_in[6];
    const float* W3 = (const float*)d_in[7];
    const float* b3 = (const float*)d_in[8];
    const float* W4 = (const float*)d_in[9];
    const float* b4 = (const float*)d_in[10];
    const float* W5 = (const float*)d_in[11];
    const float* b5 = (const float*)d_in[12];

    char* ws = (char*)d_ws;
    bf16_t* Wf  = (bf16_t*)(ws + OFF_WF);
    bf16_t* Wgf = (bf16_t*)(ws + OFF_WGF);
    float*  outp = (float*)d_out;

    build_frags<<<dim3(161), dim3(256), 0, stream>>>(W1, W2, W3, W4, W5, Wg, Wf, Wgf);
    moe_main<<<dim3(BB / 64), dim3(512), 0, stream>>>(x, Wf, Wgf, bg,
                                                      b1, b2, b3, b4, b5, outp);
}